// Round 3
// baseline (262.402 us; speedup 1.0000x reference)
//
#include <hip/hip_runtime.h>
#include <hip/hip_bf16.h>

// SOM step: M=128, N=128, DIM=2048, NITER=1000, ALPHA=0.3, SIGMA=64, eps=1e-6
// ROWS = 16384; weights 16384 x 2048 fp32 (128 MiB).
//
// Inter-kernel BMU handoff: device-scope atomicMin on ONE u64 key in d_ws
// (proven safe across XCDs / graph replay in round 1). Plain-store handoff
// from 1024 blocks failed on replay (stale reads -> rate=0 -> out=w).
//
// key = (float_bits(d2) << 32) | row  -> min gives min-dist, first-index tie.
// locations input is the row-major meshgrid -> (row>>7, row&127); never loaded.

#define ROWS 16384
#define NBLK 1024
#define NWAVES 4096          // NBLK * 4 waves
#define RPW 4                // ROWS / NWAVES
#define EPS 1e-6f

typedef float fx4 __attribute__((ext_vector_type(4)));
typedef unsigned long long u64;

__global__ __launch_bounds__(256) void som_argmin(const float* __restrict__ x,
                                                  const float* __restrict__ w,
                                                  u64* __restrict__ key) {
    const int lane = threadIdx.x & 63;
    const int wid  = threadIdx.x >> 6;
    const int gw   = blockIdx.x * 4 + wid;

    fx4 xv[8];
#pragma unroll
    for (int i = 0; i < 8; ++i) xv[i] = ((const fx4*)x)[lane + i * 64];

    // all 32 row-loads issued before any compute (512 B/lane in flight)
    fx4 wv[RPW][8];
#pragma unroll
    for (int r = 0; r < RPW; ++r) {
        const fx4* wr = (const fx4*)(w + (size_t)(gw + r * NWAVES) * 2048);
#pragma unroll
        for (int i = 0; i < 8; ++i) wv[r][i] = wr[lane + i * 64];
    }

    u64 best = ~0ULL;
#pragma unroll
    for (int r = 0; r < RPW; ++r) {
        float acc = 0.0f;
#pragma unroll
        for (int i = 0; i < 8; ++i) {
            fx4 d = xv[i] - wv[r][i] + EPS;
            acc += d.x * d.x + d.y * d.y + d.z * d.z + d.w * d.w;
        }
#pragma unroll
        for (int off = 32; off > 0; off >>= 1) acc += __shfl_xor(acc, off);
        u64 k = ((u64)__float_as_uint(acc) << 32) | (unsigned)(gw + r * NWAVES);
        best = best < k ? best : k;
    }

    __shared__ u64 sk[4];
    if (lane == 0) sk[wid] = best;
    __syncthreads();
    if (threadIdx.x == 0) {
        u64 b0 = sk[0] < sk[1] ? sk[0] : sk[1];
        u64 b1 = sk[2] < sk[3] ? sk[2] : sk[3];
        u64 b  = b0 < b1 ? b0 : b1;
        atomicMin(key, b);   // device-scope; coherent across XCDs
    }
}

__global__ __launch_bounds__(256) void som_update(const float* __restrict__ x,
                                                  const float* __restrict__ w,
                                                  const u64* __restrict__ key,
                                                  const int* __restrict__ itp,
                                                  float* __restrict__ out) {
    const int lane = threadIdx.x & 63;
    const int wid  = threadIdx.x >> 6;
    const int gw   = blockIdx.x * 4 + wid;

    const int bmu = (int)(unsigned)(*key & 0xFFFFFFFFULL);
    const float bi = (float)(bmu >> 7);
    const float bj = (float)(bmu & 127);

    const float lr       = 1.0f - (float)(*itp) / 1000.0f;
    const float alpha_op = 0.3f * lr;
    const float sigma_op = 64.0f * lr;
    const float s2       = sigma_op * sigma_op;

    fx4 xv[8];
#pragma unroll
    for (int i = 0; i < 8; ++i) xv[i] = ((const fx4*)x)[lane + i * 64];

    float rate[RPW];
#pragma unroll
    for (int r = 0; r < RPW; ++r) {
        const int row = gw + r * NWAVES;
        const float di = (float)(row >> 7) - bi;
        const float dj = (float)(row & 127) - bj;
        const float gd2 = di * di + dj * dj;
        rate[r] = alpha_op * expf(-(gd2 / s2));
    }

    fx4 wv[RPW][8];
#pragma unroll
    for (int r = 0; r < RPW; ++r) {
        const fx4* wr = (const fx4*)(w + (size_t)(gw + r * NWAVES) * 2048);
#pragma unroll
        for (int i = 0; i < 8; ++i) wv[r][i] = wr[lane + i * 64];
    }

#pragma unroll
    for (int r = 0; r < RPW; ++r) {
        fx4* orow = (fx4*)(out + (size_t)(gw + r * NWAVES) * 2048);
#pragma unroll
        for (int i = 0; i < 8; ++i)
            orow[lane + i * 64] = wv[r][i] + rate[r] * (xv[i] - wv[r][i]);
    }
}

extern "C" void kernel_launch(void* const* d_in, const int* in_sizes, int n_in,
                              void* d_out, int out_size, void* d_ws, size_t ws_size,
                              hipStream_t stream) {
    const float* x = (const float*)d_in[0];
    const float* w = (const float*)d_in[1];
    // d_in[2] = locations: row-major meshgrid, recomputed analytically; unused.
    const int* itp = (const int*)d_in[3];
    float* out = (float*)d_out;
    u64* key = (u64*)d_ws;

    // seed the argmin key with all-ones (don't rely on poison contents)
    hipMemsetAsync(d_ws, 0xFF, sizeof(u64), stream);

    som_argmin<<<NBLK, 256, 0, stream>>>(x, w, key);
    som_update<<<NBLK, 256, 0, stream>>>(x, w, key, itp, out);
}

// Round 4
// 256.912 us; speedup vs baseline: 1.0214x; 1.0214x over previous
//
#include <hip/hip_runtime.h>
#include <hip/hip_bf16.h>

// SOM step: M=128, N=128, DIM=2048, NITER=1000, ALPHA=0.3, SIGMA=64, eps=1e-6
// ROWS = 16384; weights 16384 x 2048 fp32 (128 MiB).
//
// Structure: 2048 blocks x 4 waves, 2 rows/wave (row gw and gw+8192).
//   ~120 VGPRs -> 16 waves/CU (vs 8 at the old 4-rows/wave) for continuous
//   HBM load streams via TLP.
// BMU handoff: atomicMin into 64 cache-line-padded u64 slots (d_ws), seeded
//   0xFF by memset. Atomic-write -> next-kernel plain-read is the proven-safe
//   cross-XCD path (round 1/3); plain-store handoff failed on replay (round 2).
// key = (float_bits(d2) << 32) | row -> min = min-dist, first-index tiebreak.
// update: out stores are nontemporal so the 128 MiB out stream doesn't evict
//   the L3-resident weights being re-read.
// locations input = row-major meshgrid -> (row>>7, row&127); never loaded.

#define ROWS 16384
#define NBLK 2048
#define NWAVES 8192          // NBLK * 4
#define EPS 1e-6f
#define KSLOTS 64
#define KPAD 8               // u64s per slot = 64 B (own cache line)

typedef float fx4 __attribute__((ext_vector_type(4)));
typedef unsigned long long u64;

__device__ __forceinline__ u64 u64min(u64 a, u64 b) { return a < b ? a : b; }

__global__ __launch_bounds__(256) void som_argmin(const float* __restrict__ x,
                                                  const float* __restrict__ w,
                                                  u64* __restrict__ keys) {
    const int lane = threadIdx.x & 63;
    const int wid  = threadIdx.x >> 6;
    const int gw   = blockIdx.x * 4 + wid;

    fx4 xv[8];
#pragma unroll
    for (int i = 0; i < 8; ++i) xv[i] = ((const fx4*)x)[lane + i * 64];

    const fx4* r0 = (const fx4*)(w + (size_t)gw * 2048);
    const fx4* r1 = (const fx4*)(w + (size_t)(gw + NWAVES) * 2048);
    fx4 a[8], b[8];
#pragma unroll
    for (int i = 0; i < 8; ++i) a[i] = r0[lane + i * 64];
#pragma unroll
    for (int i = 0; i < 8; ++i) b[i] = r1[lane + i * 64];

    float acc0 = 0.0f, acc1 = 0.0f;
#pragma unroll
    for (int i = 0; i < 8; ++i) {
        fx4 d = xv[i] - a[i] + EPS;
        acc0 += d.x * d.x + d.y * d.y + d.z * d.z + d.w * d.w;
    }
#pragma unroll
    for (int i = 0; i < 8; ++i) {
        fx4 d = xv[i] - b[i] + EPS;
        acc1 += d.x * d.x + d.y * d.y + d.z * d.z + d.w * d.w;
    }
#pragma unroll
    for (int off = 32; off > 0; off >>= 1) {
        acc0 += __shfl_xor(acc0, off);
        acc1 += __shfl_xor(acc1, off);
    }

    u64 k0 = ((u64)__float_as_uint(acc0) << 32) | (unsigned)gw;
    u64 k1 = ((u64)__float_as_uint(acc1) << 32) | (unsigned)(gw + NWAVES);
    u64 best = u64min(k0, k1);

    __shared__ u64 sk[4];
    if (lane == 0) sk[wid] = best;
    __syncthreads();
    if (threadIdx.x == 0) {
        u64 m = u64min(u64min(sk[0], sk[1]), u64min(sk[2], sk[3]));
        atomicMin(&keys[(blockIdx.x & (KSLOTS - 1)) * KPAD], m);
    }
}

__global__ __launch_bounds__(256) void som_update(const float* __restrict__ x,
                                                  const float* __restrict__ w,
                                                  const u64* __restrict__ keys,
                                                  const int* __restrict__ itp,
                                                  float* __restrict__ out) {
    const int lane = threadIdx.x & 63;
    const int wid  = threadIdx.x >> 6;
    const int gw   = blockIdx.x * 4 + wid;

    // issue the long-pole loads first
    const fx4* r0 = (const fx4*)(w + (size_t)gw * 2048);
    const fx4* r1 = (const fx4*)(w + (size_t)(gw + NWAVES) * 2048);
    fx4 a[8], b[8];
#pragma unroll
    for (int i = 0; i < 8; ++i) a[i] = r0[lane + i * 64];
#pragma unroll
    for (int i = 0; i < 8; ++i) b[i] = r1[lane + i * 64];

    fx4 xv[8];
#pragma unroll
    for (int i = 0; i < 8; ++i) xv[i] = ((const fx4*)x)[lane + i * 64];

    // global BMU: lane l reads slot l, butterfly min (all lanes end with min)
    u64 k = keys[lane * KPAD];
#pragma unroll
    for (int off = 32; off > 0; off >>= 1) {
        u64 o = __shfl_xor(k, off);
        k = o < k ? o : k;
    }
    const int bmu = (int)(unsigned)(k & 0xFFFFFFFFULL);
    const float bi = (float)(bmu >> 7);
    const float bj = (float)(bmu & 127);

    const float lr       = 1.0f - (float)(*itp) / 1000.0f;
    const float alpha_op = 0.3f * lr;
    const float sigma_op = 64.0f * lr;
    const float s2       = sigma_op * sigma_op;

    const int row0 = gw, row1 = gw + NWAVES;
    float di0 = (float)(row0 >> 7) - bi, dj0 = (float)(row0 & 127) - bj;
    float di1 = (float)(row1 >> 7) - bi, dj1 = (float)(row1 & 127) - bj;
    const float rate0 = alpha_op * expf(-((di0 * di0 + dj0 * dj0) / s2));
    const float rate1 = alpha_op * expf(-((di1 * di1 + dj1 * dj1) / s2));

    fx4* o0 = (fx4*)(out + (size_t)row0 * 2048);
    fx4* o1 = (fx4*)(out + (size_t)row1 * 2048);
#pragma unroll
    for (int i = 0; i < 8; ++i) {
        fx4 v = a[i] + rate0 * (xv[i] - a[i]);
        __builtin_nontemporal_store(v, &o0[lane + i * 64]);
    }
#pragma unroll
    for (int i = 0; i < 8; ++i) {
        fx4 v = b[i] + rate1 * (xv[i] - b[i]);
        __builtin_nontemporal_store(v, &o1[lane + i * 64]);
    }
}

extern "C" void kernel_launch(void* const* d_in, const int* in_sizes, int n_in,
                              void* d_out, int out_size, void* d_ws, size_t ws_size,
                              hipStream_t stream) {
    const float* x = (const float*)d_in[0];
    const float* w = (const float*)d_in[1];
    // d_in[2] = locations: row-major meshgrid, recomputed analytically; unused.
    const int* itp = (const int*)d_in[3];
    float* out = (float*)d_out;
    u64* keys = (u64*)d_ws;

    // seed all 64 key slots with all-ones
    hipMemsetAsync(d_ws, 0xFF, KSLOTS * KPAD * sizeof(u64), stream);

    som_argmin<<<NBLK, 256, 0, stream>>>(x, w, keys);
    som_update<<<NBLK, 256, 0, stream>>>(x, w, keys, itp, out);
}

// Round 14
// 255.791 us; speedup vs baseline: 1.0258x; 1.0044x over previous
//
#include <hip/hip_runtime.h>
#include <hip/hip_bf16.h>

// SOM step: M=128, N=128, DIM=2048, NITER=1000, ALPHA=0.3, SIGMA=64, eps=1e-6
// ROWS = 16384; weights 16384 x 2048 fp32 (128 MiB).
//
// TWO dispatches (memset node eliminated):
//   argmin: 2048 blocks x 4 waves, 2 rows/wave; block-best key
//           (float_bits(d2)<<32 | row) written via atomicExch to the block's
//           OWN slot keys[blockIdx] -- no init needed (every slot written
//           every call), atomic path = proven cross-XCD-coherent handoff
//           (rounds 1/3/4; plain stores failed on graph replay in round 2).
//   update: block-reduce the 2048 keys -> BMU (plain loads of atomically
//           written data: proven safe), then out = w + rate*(x-w),
//           rate = alpha_op*exp(-grid_d2/sigma_op^2); nontemporal stores.
// locations input = row-major meshgrid -> (row>>7, row&127); never loaded.
// bmu_loc_1d in the reference is dead code. Cooperative fusion rejected by
// this harness (round 9: launch silently failed, out stayed zero).

#define ROWS 16384
#define NBLK 2048
#define NWAVES 8192          // NBLK * 4
#define EPS 1e-6f

typedef float fx4 __attribute__((ext_vector_type(4)));
typedef unsigned long long u64;

__device__ __forceinline__ u64 u64min(u64 a, u64 b) { return a < b ? a : b; }

__global__ __launch_bounds__(256) void som_argmin(const float* __restrict__ x,
                                                  const float* __restrict__ w,
                                                  u64* __restrict__ keys) {
    const int lane = threadIdx.x & 63;
    const int wid  = threadIdx.x >> 6;
    const int gw   = blockIdx.x * 4 + wid;

    fx4 xv[8];
#pragma unroll
    for (int i = 0; i < 8; ++i) xv[i] = ((const fx4*)x)[lane + i * 64];

    // both rows' loads issued before any compute (256 B/lane in flight)
    const fx4* r0 = (const fx4*)(w + (size_t)gw * 2048);
    const fx4* r1 = (const fx4*)(w + (size_t)(gw + NWAVES) * 2048);
    fx4 a[8], b[8];
#pragma unroll
    for (int i = 0; i < 8; ++i) a[i] = r0[lane + i * 64];
#pragma unroll
    for (int i = 0; i < 8; ++i) b[i] = r1[lane + i * 64];

    float acc0 = 0.0f, acc1 = 0.0f;
#pragma unroll
    for (int i = 0; i < 8; ++i) {
        fx4 d = xv[i] - a[i] + EPS;
        acc0 += d.x * d.x + d.y * d.y + d.z * d.z + d.w * d.w;
    }
#pragma unroll
    for (int i = 0; i < 8; ++i) {
        fx4 d = xv[i] - b[i] + EPS;
        acc1 += d.x * d.x + d.y * d.y + d.z * d.z + d.w * d.w;
    }
#pragma unroll
    for (int off = 32; off > 0; off >>= 1) {
        acc0 += __shfl_xor(acc0, off);
        acc1 += __shfl_xor(acc1, off);
    }

    u64 k0 = ((u64)__float_as_uint(acc0) << 32) | (unsigned)gw;
    u64 k1 = ((u64)__float_as_uint(acc1) << 32) | (unsigned)(gw + NWAVES);
    u64 best = u64min(k0, k1);

    __shared__ u64 sk[4];
    if (lane == 0) sk[wid] = best;
    __syncthreads();
    if (threadIdx.x == 0) {
        u64 m = u64min(u64min(sk[0], sk[1]), u64min(sk[2], sk[3]));
        atomicExch(&keys[blockIdx.x], m);   // own slot: store with atomic
                                            // (device-coherent) semantics
    }
}

__global__ __launch_bounds__(256) void som_update(const float* __restrict__ x,
                                                  const float* __restrict__ w,
                                                  const u64* __restrict__ keys,
                                                  const int* __restrict__ itp,
                                                  float* __restrict__ out) {
    const int tid  = threadIdx.x;
    const int lane = tid & 63;
    const int wid  = tid >> 6;
    const int gw   = blockIdx.x * 4 + wid;

    // issue the long-pole row loads first
    const fx4* r0 = (const fx4*)(w + (size_t)gw * 2048);
    const fx4* r1 = (const fx4*)(w + (size_t)(gw + NWAVES) * 2048);
    fx4 a[8], b[8];
#pragma unroll
    for (int i = 0; i < 8; ++i) a[i] = r0[lane + i * 64];
#pragma unroll
    for (int i = 0; i < 8; ++i) b[i] = r1[lane + i * 64];

    fx4 xv[8];
#pragma unroll
    for (int i = 0; i < 8; ++i) xv[i] = ((const fx4*)x)[lane + i * 64];

    // ---- reduce 2048 per-block keys -> global BMU (redundant per block) ----
    u64 kk = keys[tid];
#pragma unroll
    for (int i = 1; i < 8; ++i) kk = u64min(kk, keys[tid + i * 256]);
#pragma unroll
    for (int off = 32; off > 0; off >>= 1) {
        u64 o = __shfl_xor(kk, off);
        kk = u64min(kk, o);
    }
    __shared__ u64 sb[4];
    if (lane == 0) sb[wid] = kk;
    __syncthreads();
    const u64 bb = u64min(u64min(sb[0], sb[1]), u64min(sb[2], sb[3]));

    const int bmu = (int)(unsigned)(bb & 0xFFFFFFFFULL);
    const float bi = (float)(bmu >> 7);
    const float bj = (float)(bmu & 127);

    const float lr       = 1.0f - (float)(*itp) / 1000.0f;
    const float alpha_op = 0.3f * lr;
    const float sigma_op = 64.0f * lr;
    const float s2       = sigma_op * sigma_op;

    const int row0 = gw, row1 = gw + NWAVES;
    float di0 = (float)(row0 >> 7) - bi, dj0 = (float)(row0 & 127) - bj;
    float di1 = (float)(row1 >> 7) - bi, dj1 = (float)(row1 & 127) - bj;
    const float rate0 = alpha_op * expf(-((di0 * di0 + dj0 * dj0) / s2));
    const float rate1 = alpha_op * expf(-((di1 * di1 + dj1 * dj1) / s2));

    fx4* o0 = (fx4*)(out + (size_t)row0 * 2048);
    fx4* o1 = (fx4*)(out + (size_t)row1 * 2048);
#pragma unroll
    for (int i = 0; i < 8; ++i) {
        fx4 v = a[i] + rate0 * (xv[i] - a[i]);
        __builtin_nontemporal_store(v, &o0[lane + i * 64]);
    }
#pragma unroll
    for (int i = 0; i < 8; ++i) {
        fx4 v = b[i] + rate1 * (xv[i] - b[i]);
        __builtin_nontemporal_store(v, &o1[lane + i * 64]);
    }
}

extern "C" void kernel_launch(void* const* d_in, const int* in_sizes, int n_in,
                              void* d_out, int out_size, void* d_ws, size_t ws_size,
                              hipStream_t stream) {
    const float* x = (const float*)d_in[0];
    const float* w = (const float*)d_in[1];
    // d_in[2] = locations: row-major meshgrid, recomputed analytically; unused.
    const int* itp = (const int*)d_in[3];
    float* out = (float*)d_out;
    u64* keys = (u64*)d_ws;   // NBLK slots, each written every call (atomicExch)

    som_argmin<<<NBLK, 256, 0, stream>>>(x, w, keys);
    som_update<<<NBLK, 256, 0, stream>>>(x, w, keys, itp, out);
}